// Round 5
// baseline (844.784 us; speedup 1.0000x reference)
//
#include <hip/hip_runtime.h>

#define N 8192
#define F 128
#define NS 4             // j-splits
#define JT (N / NS)      // 2048 j per block
#define CJ 64            // j per chunk
#define NC (JT / CJ)     // 32 chunks
#define TI 32            // i-rows per block
#define ALPHA 0.2f

typedef __attribute__((ext_vector_type(8))) short short8;
typedef __attribute__((ext_vector_type(4))) float f32x4;
typedef unsigned short u16;

__device__ __forceinline__ u16 f2bf(float f) {
    unsigned int u = __float_as_uint(f);
    u += 0x7fff + ((u >> 16) & 1);  // RNE; finite inputs
    return (u16)(u >> 16);
}
__device__ __forceinline__ float bf2f(u16 b) {
    return __uint_as_float(((unsigned int)b) << 16);
}
__device__ __forceinline__ float lrelu(float z) { return fmaxf(z, ALPHA * z); }

// async global->LDS, 16B per lane; LDS dest is wave-uniform base + lane*16
__device__ __forceinline__ void dma16(const void* g, void* l) {
    __builtin_amdgcn_global_load_lds((__attribute__((address_space(1))) void*)g,
                                     (__attribute__((address_space(3))) void*)l, 16, 0, 0);
}

// ---------------- K1: h = x@W ; emit hT (bf16, [feature][node]) + ssrc/sdst (fp32) ----------------
__global__ __launch_bounds__(256) void gemm_h(const float* __restrict__ x,
                                              const float* __restrict__ W,
                                              const float* __restrict__ aa,
                                              u16* __restrict__ hT,
                                              float* __restrict__ ssrc,
                                              float* __restrict__ sdst) {
    __shared__ float xs[32 * 128];
    __shared__ float Wsh[32 * 128];
    const int t = threadIdx.x;
    const int i0 = blockIdx.x * 32;
    const int c4 = (t & 31) * 4;
    const int r8 = t >> 5;

#pragma unroll
    for (int p = 0; p < 4; ++p) {
        int rr = p * 8 + r8;
        *(float4*)&xs[rr * 128 + c4] = *(const float4*)&x[(size_t)(i0 + rr) * 128 + c4];
    }

    const int tx = t & 31, ty = t >> 5;
    const int r0 = ty * 4, c0 = tx * 4;
    float acc[4][4] = {};

    for (int kc = 0; kc < 4; ++kc) {
        __syncthreads();
#pragma unroll
        for (int p = 0; p < 4; ++p) {
            int k = p * 8 + r8;
            *(float4*)&Wsh[k * 128 + c4] = *(const float4*)&W[(kc * 32 + k) * 128 + c4];
        }
        __syncthreads();
#pragma unroll 4
        for (int k = 0; k < 32; k += 4) {
            float xr[4][4];
#pragma unroll
            for (int rr = 0; rr < 4; ++rr)
                *(float4*)xr[rr] = *(const float4*)&xs[(r0 + rr) * 128 + kc * 32 + k];
#pragma unroll
            for (int kk = 0; kk < 4; ++kk) {
                float4 wv = *(const float4*)&Wsh[(k + kk) * 128 + c0];
#pragma unroll
                for (int rr = 0; rr < 4; ++rr) {
                    acc[rr][0] += xr[rr][kk] * wv.x;
                    acc[rr][1] += xr[rr][kk] * wv.y;
                    acc[rr][2] += xr[rr][kk] * wv.z;
                    acc[rr][3] += xr[rr][kk] * wv.w;
                }
            }
        }
    }

#pragma unroll
    for (int rr = 0; rr < 4; ++rr)
#pragma unroll
        for (int cc = 0; cc < 4; ++cc)
            hT[(size_t)(c0 + cc) * N + (i0 + r0 + rr)] = f2bf(acc[rr][cc]);

    float4 asv = *(const float4*)&aa[c0];
    float4 adv = *(const float4*)&aa[F + c0];
#pragma unroll
    for (int rr = 0; rr < 4; ++rr) {
        float vs = acc[rr][0] * asv.x + acc[rr][1] * asv.y + acc[rr][2] * asv.z + acc[rr][3] * asv.w;
        float vd = acc[rr][0] * adv.x + acc[rr][1] * adv.y + acc[rr][2] * adv.z + acc[rr][3] * adv.w;
#pragma unroll
        for (int off = 16; off >= 1; off >>= 1) {
            vs += __shfl_down(vs, off, 32);
            vd += __shfl_down(vd, off, 32);
        }
        if (tx == 0) {
            ssrc[i0 + r0 + rr] = vs;
            sdst[i0 + r0 + rr] = vd;
        }
    }
}

// ---------------- K2: attention. ONE barrier/chunk; in-lane A-frags; hT tile via dbuf DMA. ----------------
// Wave w: rows rt*16+l16 (rt=w&1), feature cols [(w>>1)*64, +64). Every vmem op gets a
// full phase of cover before the single per-chunk barrier drains it.
__global__ __launch_bounds__(256, 4) void attn_mfma(const int* __restrict__ adj,
                                                    const u16* __restrict__ hT,
                                                    const float* __restrict__ ssrc,
                                                    const float* __restrict__ sdst,
                                                    float* __restrict__ pacc,
                                                    float* __restrict__ pS) {
    __shared__ u16 bt[2][128 * CJ];  // 2 x 16 KB, [feat][j-slot XOR-swizzled]

    const int t = threadIdx.x;
    const int w = t >> 6, L = t & 63;
    const int quad = L >> 4, l16 = L & 15;
    const int i0 = blockIdx.x * TI;
    const int split = blockIdx.y;
    const int j0 = split * JT;

    const int rt = w & 1;
    const int colbase = (w >> 1) * 4;
    const int row = i0 + rt * 16 + l16;
    const float s_i = ssrc[row];

    const int* pA = adj + (size_t)row * N + j0 + quad * 8;  // + ks*32 + c*CJ
    const float* pD = sdst + j0 + quad * 8;

    // DMA roles: thread t stages feat bf=t>>3 (+rp*32), slot t&7 holds j-block (t&7)^(bf&7)
    const int bf = t >> 3;
    const int bsj = (t & 7) ^ (bf & 7);
    const u16* pG = hT + (size_t)bf * N + j0 + bsj * 8;  // + rp*32*N + c*CJ

    f32x4 acc[4];
#pragma unroll
    for (int ci = 0; ci < 4; ++ci) acc[ci] = 0.f;
    float rsum = 0.f;

    // adj/sdst register slots: slot s holds chunk c with c&1==s
    int4 aj[2][2][2];
    float4 dd[2][2][2];

    // ---- prologue: DMA(0), adj(0) -> slot 0, then barrier (drains both) ----
#pragma unroll
    for (int rp = 0; rp < 4; ++rp)
        dma16(pG + (size_t)rp * 32 * N, &bt[0][rp * 2048 + w * 512]);
#pragma unroll
    for (int ks = 0; ks < 2; ++ks) {
        aj[0][ks][0] = *(const int4*)(pA + ks * 32);
        aj[0][ks][1] = *(const int4*)(pA + ks * 32 + 4);
        dd[0][ks][0] = *(const float4*)(pD + ks * 32);
        dd[0][ks][1] = *(const float4*)(pD + ks * 32 + 4);
    }
    __syncthreads();

    for (int c = 0; c < NC; ++c) {
        const int cn = (c + 1 < NC) ? c + 1 : c;
        const int sl = (c + 1) & 1;

        // issue DMA(c+1) into bt[(c+1)&1] (read next phase, drained at this phase's barrier)
        {
            u16* db = bt[sl];
#pragma unroll
            for (int rp = 0; rp < 4; ++rp)
                dma16(pG + (size_t)rp * 32 * N + cn * CJ, &db[rp * 2048 + w * 512]);
        }
        // issue adj/sdst(c+1) into slot sl (consumed next phase: full phase of cover)
#pragma unroll
        for (int ks = 0; ks < 2; ++ks) {
            aj[sl][ks][0] = *(const int4*)(pA + cn * CJ + ks * 32);
            aj[sl][ks][1] = *(const int4*)(pA + cn * CJ + ks * 32 + 4);
            dd[sl][ks][0] = *(const float4*)(pD + cn * CJ + ks * 32);
            dd[sl][ks][1] = *(const float4*)(pD + cn * CJ + ks * 32 + 4);
        }

        // compute A(c) in-lane from slot c&1 (loaded a full phase ago)
        short8 A[2];
#pragma unroll
        for (int ks = 0; ks < 2; ++ks) {
            const int s = c & 1;
            int m[8] = {aj[s][ks][0].x, aj[s][ks][0].y, aj[s][ks][0].z, aj[s][ks][0].w,
                        aj[s][ks][1].x, aj[s][ks][1].y, aj[s][ks][1].z, aj[s][ks][1].w};
            float d[8] = {dd[s][ks][0].x, dd[s][ks][0].y, dd[s][ks][0].z, dd[s][ks][0].w,
                          dd[s][ks][1].x, dd[s][ks][1].y, dd[s][ks][1].z, dd[s][ks][1].w};
#pragma unroll
            for (int k = 0; k < 8; ++k) {
                float e = __expf(lrelu(s_i + d[k]));
                u16 b = f2bf(m[k] > 0 ? e : 0.f);
                rsum += bf2f(b);
                A[ks][k] = (short)b;
            }
        }

        // MFMA(c): B from bt[c&1] (DMA drained at previous barrier)
        const u16* btc = bt[c & 1];
#pragma unroll
        for (int ks = 0; ks < 2; ++ks) {
#pragma unroll
            for (int ci = 0; ci < 4; ++ci) {
                const int f = (colbase + ci) * 16 + l16;
                const int s = (ks * 4 + quad) ^ (f & 7);
                short8 B = *(const short8*)&btc[(f >> 5) * 2048 + (f & 31) * 64 + s * 8];
                acc[ci] = __builtin_amdgcn_mfma_f32_16x16x32_bf16(A[ks], B, acc[ci], 0, 0, 0);
            }
        }

        __syncthreads();  // single drain point: DMA(c+1) + adj(c+1) have a full phase of cover
    }

    // store partials: D layout col=lane&15, row=quad*4+reg
    float* dst = pacc + (size_t)split * N * F;
#pragma unroll
    for (int ci = 0; ci < 4; ++ci) {
        const int col = (colbase + ci) * 16 + l16;
        const int r0 = i0 + rt * 16 + quad * 4;
#pragma unroll
        for (int r = 0; r < 4; ++r)
            dst[(size_t)(r0 + r) * F + col] = acc[ci][r];
    }

    // row sums (waves 0,1 only — waves 2,3 hold duplicates); reduce over quads
    rsum += __shfl_xor(rsum, 16);
    rsum += __shfl_xor(rsum, 32);
    if (w < 2 && L < 16)
        pS[(size_t)split * N + i0 + rt * 16 + l16] = rsum;
}

// ---------------- K3: out = (sum_s pacc_s) / (sum_s pS_s) ----------------
__global__ __launch_bounds__(256) void finalize(float* __restrict__ out,
                                                const float* __restrict__ pacc,
                                                const float* __restrict__ pS) {
    const int idx = (blockIdx.x * 256 + threadIdx.x) * 4;
    const int i = idx >> 7;
    float s = 0.f;
#pragma unroll
    for (int k = 0; k < NS; ++k) s += pS[(size_t)k * N + i];
    float4 a = {0.f, 0.f, 0.f, 0.f};
#pragma unroll
    for (int k = 0; k < NS; ++k) {
        float4 v = *(const float4*)&pacc[(size_t)k * N * F + idx];
        a.x += v.x; a.y += v.y; a.z += v.z; a.w += v.w;
    }
    const float inv = 1.0f / s;
    float4 o = {a.x * inv, a.y * inv, a.z * inv, a.w * inv};
    *(float4*)&out[idx] = o;
}

extern "C" void kernel_launch(void* const* d_in, const int* in_sizes, int n_in,
                              void* d_out, int out_size, void* d_ws, size_t ws_size,
                              hipStream_t stream) {
    (void)in_sizes; (void)n_in; (void)out_size; (void)ws_size;
    const float* x   = (const float*)d_in[0];
    const int*   adj = (const int*)d_in[1];
    const float* W   = (const float*)d_in[2];
    const float* a   = (const float*)d_in[3];
    float* out = (float*)d_out;

    u16* hT     = (u16*)d_ws;                    // N*F bf16 (2 MB)
    float* ssrc = (float*)(hT + (size_t)N * F);  // N
    float* sdst = ssrc + N;                      // N
    float* pS   = sdst + N;                      // NS*N
    float* pacc = pS + (size_t)NS * N;           // NS*N*F fp32 (16 MB)

    gemm_h<<<N / 32, 256, 0, stream>>>(x, W, a, hT, ssrc, sdst);
    attn_mfma<<<dim3(N / TI, NS), 256, 0, stream>>>(adj, hT, ssrc, sdst, pacc, pS);
    finalize<<<(N * F / 4) / 256, 256, 0, stream>>>(out, pacc, pS);
}

// Round 6
// 435.781 us; speedup vs baseline: 1.9386x; 1.9386x over previous
//
#include <hip/hip_runtime.h>

#define N 8192
#define F 128
#define NS 4             // j-splits
#define JT (N / NS)      // 2048 j per block
#define CJ 64            // j per chunk
#define NC (JT / CJ)     // 32 chunks (even)
#define TI 32            // i-rows per block
#define ALPHA 0.2f

typedef __attribute__((ext_vector_type(8))) short short8;
typedef __attribute__((ext_vector_type(4))) float f32x4;
typedef unsigned short u16;

__device__ __forceinline__ u16 f2bf(float f) {
    unsigned int u = __float_as_uint(f);
    u += 0x7fff + ((u >> 16) & 1);  // RNE; finite inputs
    return (u16)(u >> 16);
}
__device__ __forceinline__ float bf2f(u16 b) {
    return __uint_as_float(((unsigned int)b) << 16);
}
__device__ __forceinline__ float lrelu(float z) { return fmaxf(z, ALPHA * z); }

// async global->LDS, 16B per lane; LDS dest is wave-uniform base + lane*16
__device__ __forceinline__ void dma16(const void* g, void* l) {
    __builtin_amdgcn_global_load_lds((__attribute__((address_space(1))) void*)g,
                                     (__attribute__((address_space(3))) void*)l, 16, 0, 0);
}

// ---------------- K1: h = x@W ; emit hT (bf16, [feature][node]) + ssrc/sdst (fp32) ----------------
__global__ __launch_bounds__(256) void gemm_h(const float* __restrict__ x,
                                              const float* __restrict__ W,
                                              const float* __restrict__ aa,
                                              u16* __restrict__ hT,
                                              float* __restrict__ ssrc,
                                              float* __restrict__ sdst) {
    __shared__ float xs[32 * 128];
    __shared__ float Wsh[32 * 128];
    const int t = threadIdx.x;
    const int i0 = blockIdx.x * 32;
    const int c4 = (t & 31) * 4;
    const int r8 = t >> 5;

#pragma unroll
    for (int p = 0; p < 4; ++p) {
        int rr = p * 8 + r8;
        *(float4*)&xs[rr * 128 + c4] = *(const float4*)&x[(size_t)(i0 + rr) * 128 + c4];
    }

    const int tx = t & 31, ty = t >> 5;
    const int r0 = ty * 4, c0 = tx * 4;
    float acc[4][4] = {};

    for (int kc = 0; kc < 4; ++kc) {
        __syncthreads();
#pragma unroll
        for (int p = 0; p < 4; ++p) {
            int k = p * 8 + r8;
            *(float4*)&Wsh[k * 128 + c4] = *(const float4*)&W[(kc * 32 + k) * 128 + c4];
        }
        __syncthreads();
#pragma unroll 4
        for (int k = 0; k < 32; k += 4) {
            float xr[4][4];
#pragma unroll
            for (int rr = 0; rr < 4; ++rr)
                *(float4*)xr[rr] = *(const float4*)&xs[(r0 + rr) * 128 + kc * 32 + k];
#pragma unroll
            for (int kk = 0; kk < 4; ++kk) {
                float4 wv = *(const float4*)&Wsh[(k + kk) * 128 + c0];
#pragma unroll
                for (int rr = 0; rr < 4; ++rr) {
                    acc[rr][0] += xr[rr][kk] * wv.x;
                    acc[rr][1] += xr[rr][kk] * wv.y;
                    acc[rr][2] += xr[rr][kk] * wv.z;
                    acc[rr][3] += xr[rr][kk] * wv.w;
                }
            }
        }
    }

#pragma unroll
    for (int rr = 0; rr < 4; ++rr)
#pragma unroll
        for (int cc = 0; cc < 4; ++cc)
            hT[(size_t)(c0 + cc) * N + (i0 + r0 + rr)] = f2bf(acc[rr][cc]);

    float4 asv = *(const float4*)&aa[c0];
    float4 adv = *(const float4*)&aa[F + c0];
#pragma unroll
    for (int rr = 0; rr < 4; ++rr) {
        float vs = acc[rr][0] * asv.x + acc[rr][1] * asv.y + acc[rr][2] * asv.z + acc[rr][3] * asv.w;
        float vd = acc[rr][0] * adv.x + acc[rr][1] * adv.y + acc[rr][2] * adv.z + acc[rr][3] * adv.w;
#pragma unroll
        for (int off = 16; off >= 1; off >>= 1) {
            vs += __shfl_down(vs, off, 32);
            vd += __shfl_down(vd, off, 32);
        }
        if (tx == 0) {
            ssrc[i0 + r0 + rr] = vs;
            sdst[i0 + r0 + rr] = vd;
        }
    }
}

// ---------------- K2: attention. ONE barrier/chunk; named dbuf register slots (no scratch). ----------------
__global__ __launch_bounds__(256, 4) void attn_mfma(const int* __restrict__ adj,
                                                    const u16* __restrict__ hT,
                                                    const float* __restrict__ ssrc,
                                                    const float* __restrict__ sdst,
                                                    float* __restrict__ pacc,
                                                    float* __restrict__ pS) {
    __shared__ u16 bt0[128 * CJ];  // 16 KB, [feat][j-slot XOR-swizzled]
    __shared__ u16 bt1[128 * CJ];  // 16 KB

    const int t = threadIdx.x;
    const int w = t >> 6, L = t & 63;
    const int quad = L >> 4, l16 = L & 15;
    const int i0 = blockIdx.x * TI;
    const int split = blockIdx.y;
    const int j0 = split * JT;

    const int rt = w & 1;
    const int colbase = (w >> 1) * 4;
    const int row = i0 + rt * 16 + l16;
    const float s_i = ssrc[row];

    const int* pA = adj + (size_t)row * N + j0 + quad * 8;  // + ks*32 + c*CJ
    const float* pD = sdst + j0 + quad * 8;

    // DMA roles: thread t stages feat bf=t>>3 (+rp*32), slot t&7 holds j-block (t&7)^(bf&7)
    const int bf = t >> 3;
    const int bsj = (t & 7) ^ (bf & 7);
    const u16* pG = hT + (size_t)bf * N + j0 + bsj * 8;  // + rp*32*N + c*CJ

    f32x4 acc[4];
#pragma unroll
    for (int ci = 0; ci < 4; ++ci) acc[ci] = 0.f;
    float rsum = 0.f;

    // named double-buffer register slots (all indices compile-time constant)
    int4 ajA[2][2], ajB[2][2];
    float4 ddA[2][2], ddB[2][2];

    // ---- prologue: DMA(0)->bt0, adj(0)->slot A, barrier drains DMA(0) ----
#pragma unroll
    for (int rp = 0; rp < 4; ++rp)
        dma16(pG + (size_t)rp * 32 * N, &bt0[rp * 2048 + w * 512]);
#pragma unroll
    for (int ks = 0; ks < 2; ++ks) {
        ajA[ks][0] = *(const int4*)(pA + ks * 32);
        ajA[ks][1] = *(const int4*)(pA + ks * 32 + 4);
        ddA[ks][0] = *(const float4*)(pD + ks * 32);
        ddA[ks][1] = *(const float4*)(pD + ks * 32 + 4);
    }
    __syncthreads();

    // phase body: consume slot C (chunk c) + btc; prefetch chunk c+1 into slot N + btn
    auto phase = [&](int c, int4 (&ajC)[2][2], float4 (&ddC)[2][2],
                     int4 (&ajN)[2][2], float4 (&ddN)[2][2],
                     const u16* btc, u16* btn) __attribute__((always_inline)) {
        const int cn = (c + 1 < NC) ? c + 1 : c;

        // issue DMA(c+1) into btn (drained at this phase's barrier: full phase of cover)
#pragma unroll
        for (int rp = 0; rp < 4; ++rp)
            dma16(pG + (size_t)rp * 32 * N + cn * CJ, &btn[rp * 2048 + w * 512]);

        // issue adj/sdst(c+1) into slot N (consumed next phase)
#pragma unroll
        for (int ks = 0; ks < 2; ++ks) {
            ajN[ks][0] = *(const int4*)(pA + cn * CJ + ks * 32);
            ajN[ks][1] = *(const int4*)(pA + cn * CJ + ks * 32 + 4);
            ddN[ks][0] = *(const float4*)(pD + cn * CJ + ks * 32);
            ddN[ks][1] = *(const float4*)(pD + cn * CJ + ks * 32 + 4);
        }

        // compute A(c) in-lane from slot C (loaded a full phase ago)
        short8 A[2];
#pragma unroll
        for (int ks = 0; ks < 2; ++ks) {
            int m[8] = {ajC[ks][0].x, ajC[ks][0].y, ajC[ks][0].z, ajC[ks][0].w,
                        ajC[ks][1].x, ajC[ks][1].y, ajC[ks][1].z, ajC[ks][1].w};
            float d[8] = {ddC[ks][0].x, ddC[ks][0].y, ddC[ks][0].z, ddC[ks][0].w,
                          ddC[ks][1].x, ddC[ks][1].y, ddC[ks][1].z, ddC[ks][1].w};
#pragma unroll
            for (int k = 0; k < 8; ++k) {
                float e = __expf(lrelu(s_i + d[k]));
                u16 b = f2bf(m[k] > 0 ? e : 0.f);
                rsum += bf2f(b);
                A[ks][k] = (short)b;
            }
        }

        // MFMA(c): B from btc (its DMA drained at the previous barrier)
#pragma unroll
        for (int ks = 0; ks < 2; ++ks) {
#pragma unroll
            for (int ci = 0; ci < 4; ++ci) {
                const int f = (colbase + ci) * 16 + l16;
                const int s = (ks * 4 + quad) ^ (f & 7);
                short8 B = *(const short8*)&btc[(f >> 5) * 2048 + (f & 31) * 64 + s * 8];
                acc[ci] = __builtin_amdgcn_mfma_f32_16x16x32_bf16(A[ks], B, acc[ci], 0, 0, 0);
            }
        }

        __syncthreads();  // single drain point per chunk
    };

    for (int c = 0; c < NC; c += 2) {
        phase(c,     ajA, ddA, ajB, ddB, bt0, bt1);
        phase(c + 1, ajB, ddB, ajA, ddA, bt1, bt0);
    }

    // store partials: D layout col=lane&15, row=quad*4+reg
    float* dst = pacc + (size_t)split * N * F;
#pragma unroll
    for (int ci = 0; ci < 4; ++ci) {
        const int col = (colbase + ci) * 16 + l16;
        const int r0 = i0 + rt * 16 + quad * 4;
#pragma unroll
        for (int r = 0; r < 4; ++r)
            dst[(size_t)(r0 + r) * F + col] = acc[ci][r];
    }

    // row sums (waves 0,1 carry canonical copies); reduce over quads
    rsum += __shfl_xor(rsum, 16);
    rsum += __shfl_xor(rsum, 32);
    if (w < 2 && L < 16)
        pS[(size_t)split * N + i0 + rt * 16 + l16] = rsum;
}

// ---------------- K3: out = (sum_s pacc_s) / (sum_s pS_s) ----------------
__global__ __launch_bounds__(256) void finalize(float* __restrict__ out,
                                                const float* __restrict__ pacc,
                                                const float* __restrict__ pS) {
    const int idx = (blockIdx.x * 256 + threadIdx.x) * 4;
    const int i = idx >> 7;
    float s = 0.f;
#pragma unroll
    for (int k = 0; k < NS; ++k) s += pS[(size_t)k * N + i];
    float4 a = {0.f, 0.f, 0.f, 0.f};
#pragma unroll
    for (int k = 0; k < NS; ++k) {
        float4 v = *(const float4*)&pacc[(size_t)k * N * F + idx];
        a.x += v.x; a.y += v.y; a.z += v.z; a.w += v.w;
    }
    const float inv = 1.0f / s;
    float4 o = {a.x * inv, a.y * inv, a.z * inv, a.w * inv};
    *(float4*)&out[idx] = o;
}

extern "C" void kernel_launch(void* const* d_in, const int* in_sizes, int n_in,
                              void* d_out, int out_size, void* d_ws, size_t ws_size,
                              hipStream_t stream) {
    (void)in_sizes; (void)n_in; (void)out_size; (void)ws_size;
    const float* x   = (const float*)d_in[0];
    const int*   adj = (const int*)d_in[1];
    const float* W   = (const float*)d_in[2];
    const float* a   = (const float*)d_in[3];
    float* out = (float*)d_out;

    u16* hT     = (u16*)d_ws;                    // N*F bf16 (2 MB)
    float* ssrc = (float*)(hT + (size_t)N * F);  // N
    float* sdst = ssrc + N;                      // N
    float* pS   = sdst + N;                      // NS*N
    float* pacc = pS + (size_t)NS * N;           // NS*N*F fp32 (16 MB)

    gemm_h<<<N / 32, 256, 0, stream>>>(x, W, a, hT, ssrc, sdst);
    attn_mfma<<<dim3(N / TI, NS), 256, 0, stream>>>(adj, hT, ssrc, sdst, pacc, pS);
    finalize<<<(N * F / 4) / 256, 256, 0, stream>>>(out, pacc, pS);
}